// Round 1
// baseline (190.342 us; speedup 1.0000x reference)
//
#include <hip/hip_runtime.h>

typedef __attribute__((ext_vector_type(8))) short bf16x8;
typedef __attribute__((ext_vector_type(4))) float f32x4;
typedef __attribute__((ext_vector_type(4))) unsigned int u32x4;
typedef __attribute__((ext_vector_type(4))) unsigned short u16x4;

__device__ __forceinline__ unsigned short f2bf_rne(float f) {
  unsigned u = __float_as_uint(f);
  u += 0x7FFFu + ((u >> 16) & 1u);
  return (unsigned short)(u >> 16);
}
__device__ __forceinline__ float bf2f(unsigned short h) {
  return __uint_as_float(((unsigned)h) << 16);
}

// ---------------- Kernel 1: prep ----------------
// codebook fp32 -> bf16 (ws), norms = sum(bf16(e)^2) (consistent with MFMA dot),
// zero the loss accumulator at d_out[N*D].
__global__ void vq_prep(const float* __restrict__ cb,
                        float* __restrict__ norms,
                        unsigned short* __restrict__ cbh,
                        float* __restrict__ loss_out) {
  if (blockIdx.x == 0 && threadIdx.x == 0) *loss_out = 0.0f;
  const int lane = threadIdx.x & 63;
  const int code = (blockIdx.x * blockDim.x + threadIdx.x) >> 6;  // one wave per code
  const f32x4 v = ((const f32x4*)(cb + (long)code * 256))[lane];
  u16x4 h;
  float n = 0.f;
#pragma unroll
  for (int j = 0; j < 4; ++j) {
    unsigned short b = f2bf_rne(v[j]);
    h[j] = (unsigned short)b;
    float bf = bf2f(b);
    n += bf * bf;
  }
  ((u16x4*)(cbh + (long)code * 256))[lane] = h;
#pragma unroll
  for (int m = 1; m < 64; m <<= 1) n += __shfl_xor(n, m);
  if (lane == 0) norms[code] = n;
}

// ---------------- Kernel 2: main ----------------
#define BM 128   // rows per block
#define BC 128   // codes per tile
#define DD 256   // embedding dim

__global__ __launch_bounds__(256, 1)
void vq_main(const float* __restrict__ X,
             const float* __restrict__ CB,
             const float* __restrict__ norms,
             const unsigned short* __restrict__ cbh,
             float* __restrict__ out,
             float* __restrict__ loss_out,
             int K, float lscale) {
  __shared__ __attribute__((aligned(16))) unsigned short Xs[BM * DD];  // 64 KiB, swizzled bf16
  __shared__ __attribute__((aligned(16))) unsigned short Es[BC * DD];  // 64 KiB, swizzled bf16

  const int t = threadIdx.x;
  const int lane = t & 63;
  const int wave = t >> 6;
  const int wr = wave >> 1;  // row half (0/1)
  const int wc = wave & 1;   // col half (0/1)
  const long rowBase = (long)blockIdx.x * BM;
  const int lo16 = lane & 15;
  const int hi = lane >> 4;

  // ---- stage X: fp32 global -> bf16 LDS (XOR swizzle byte ^= (row&7)<<4) ----
  {
    const f32x4* Xg = (const f32x4*)(X + rowBase * DD);
#pragma unroll
    for (int i = 0; i < 32; ++i) {
      int idx = t + 256 * i;  // 8192 float4 chunks
      int row = idx >> 6, d4 = idx & 63;
      f32x4 v = Xg[idx];
      u16x4 h;
#pragma unroll
      for (int j = 0; j < 4; ++j) h[j] = f2bf_rne(v[j]);
      unsigned byte = (unsigned)(row * 512 + d4 * 8);
      byte ^= (unsigned)((row & 7) << 4);
      *(u16x4*)((char*)Xs + byte) = h;
    }
  }

  float bs[4][4];
  int bi[4][4];
#pragma unroll
  for (int m = 0; m < 4; ++m)
#pragma unroll
    for (int r = 0; r < 4; ++r) { bs[m][r] = 3.0e38f; bi[m][r] = 0; }

  const int NT = K / BC;  // 8 code-tiles
  for (int ct = 0; ct < NT; ++ct) {
    // ---- stage E tile: bf16 ws -> LDS swizzled (reg-staged) ----
    {
      const u32x4* Eg = (const u32x4*)(cbh + (long)ct * BC * DD);
#pragma unroll
      for (int i = 0; i < 16; ++i) {
        int idx = t + 256 * i;  // 4096 16B chunks
        int code = idx >> 5, c16 = idx & 31;
        u32x4 v = Eg[idx];
        unsigned byte = (unsigned)(code * 512 + c16 * 16);
        byte ^= (unsigned)((code & 7) << 4);
        *(u32x4*)((char*)Es + byte) = v;
      }
    }
    __syncthreads();

    f32x4 acc[4][4];
#pragma unroll
    for (int m = 0; m < 4; ++m)
#pragma unroll
      for (int n = 0; n < 4; ++n) {
        f32x4 z = {0.f, 0.f, 0.f, 0.f};
        acc[m][n] = z;
      }

#pragma unroll 2
    for (int ks = 0; ks < 8; ++ks) {
      bf16x8 a[4], b[4];
      const unsigned kb = (unsigned)(ks * 64 + hi * 16);
#pragma unroll
      for (int m = 0; m < 4; ++m) {
        int row = wr * 64 + m * 16 + lo16;
        unsigned byte = (unsigned)(row * 512) + kb;
        byte ^= (unsigned)((row & 7) << 4);
        a[m] = *(const bf16x8*)((const char*)Xs + byte);
      }
#pragma unroll
      for (int n = 0; n < 4; ++n) {
        int code = wc * 64 + n * 16 + lo16;
        unsigned byte = (unsigned)(code * 512) + kb;
        byte ^= (unsigned)((code & 7) << 4);
        b[n] = *(const bf16x8*)((const char*)Es + byte);
      }
#pragma unroll
      for (int m = 0; m < 4; ++m)
#pragma unroll
        for (int n = 0; n < 4; ++n)
          acc[m][n] = __builtin_amdgcn_mfma_f32_16x16x32_bf16(a[m], b[n], acc[m][n], 0, 0, 0);
    }

    // ---- epilogue: score = ||e||^2 - 2 x.e ; per-row running argmin ----
    const int cbase = ct * BC + wc * 64;
    float nrm[4];
#pragma unroll
    for (int n = 0; n < 4; ++n) nrm[n] = norms[cbase + n * 16 + lo16];

#pragma unroll
    for (int m = 0; m < 4; ++m) {
#pragma unroll
      for (int r = 0; r < 4; ++r) {
        float s = nrm[0] - 2.0f * acc[m][0][r];
        int c = cbase + lo16;
#pragma unroll
        for (int n = 1; n < 4; ++n) {
          float s2 = nrm[n] - 2.0f * acc[m][n][r];
          int c2 = cbase + n * 16 + lo16;
          if (s2 < s) { s = s2; c = c2; }
        }
        // butterfly across the 16 lanes holding this row's 16 cols
#pragma unroll
        for (int msk = 1; msk < 16; msk <<= 1) {
          float s2 = __shfl_xor(s, msk);
          int c2 = __shfl_xor(c, msk);
          if (s2 < s || (s2 == s && c2 < c)) { s = s2; c = c2; }
        }
        if (s < bs[m][r]) { bs[m][r] = s; bi[m][r] = c; }
      }
    }
    __syncthreads();  // before next tile's E staging overwrites Es
  }

  // ---- merge the two col-halves per row, via LDS (Es reused) ----
  float* sA = (float*)Es;
  float* sB = sA + BM;
  int* iA = (int*)(sB + BM);
  int* iB = iA + BM;
  int* iM = iB + BM;

  if ((lane & 15) == 0) {
    float* sDst = wc ? sB : sA;
    int* iDst = wc ? iB : iA;
#pragma unroll
    for (int m = 0; m < 4; ++m)
#pragma unroll
      for (int r = 0; r < 4; ++r) {
        int rl = wr * 64 + m * 16 + hi * 4 + r;  // C/D layout: row=(lane>>4)*4+reg
        sDst[rl] = bs[m][r];
        iDst[rl] = bi[m][r];
      }
  }
  __syncthreads();
  if (t < BM) {
    float sa = sA[t], sb = sB[t];
    int ia = iA[t], ib = iB[t];
    iM[t] = (sb < sa || (sb == sa && ib < ia)) ? ib : ia;
  }
  __syncthreads();

  // ---- gather codebook rows -> output; fp32 MSE partial ----
  float ls = 0.f;
  {
    const f32x4* Xg = (const f32x4*)(X + rowBase * DD);
    f32x4* Og = (f32x4*)out + rowBase * (DD / 4);
#pragma unroll 4
    for (int i = 0; i < 32; ++i) {
      int idx = t + 256 * i;
      int row = idx >> 6, d4 = idx & 63;
      int code = iM[row];
      f32x4 e = ((const f32x4*)(CB + (long)code * DD))[d4];
      f32x4 x = Xg[idx];
      Og[idx] = e;
#pragma unroll
      for (int j = 0; j < 4; ++j) {
        float df = e[j] - x[j];
        ls += df * df;
      }
    }
  }
#pragma unroll
  for (int m = 1; m < 64; m <<= 1) ls += __shfl_xor(ls, m);
  float* wsum = (float*)Xs;  // Xs no longer needed
  if (lane == 0) wsum[wave] = ls;
  __syncthreads();
  if (t == 0) {
    float tot = wsum[0] + wsum[1] + wsum[2] + wsum[3];
    atomicAdd(loss_out, tot * lscale);
  }
}

extern "C" void kernel_launch(void* const* d_in, const int* in_sizes, int n_in,
                              void* d_out, int out_size, void* d_ws, size_t ws_size,
                              hipStream_t stream) {
  const float* X = (const float*)d_in[0];
  const float* CB = (const float*)d_in[1];
  float* out = (float*)d_out;

  const int ND = in_sizes[0];       // 16*4096*256 = 16777216
  const int K = in_sizes[1] / DD;   // 1024
  const int N = ND / DD;            // 65536

  float* ws_norms = (float*)d_ws;                                // K floats
  unsigned short* ws_cb = (unsigned short*)((char*)d_ws + (size_t)K * sizeof(float));  // K*D bf16
  float* loss_out = out + (size_t)ND;

  // one wave per code
  vq_prep<<<K / 4, 256, 0, stream>>>(CB, ws_norms, ws_cb, loss_out);

  const float lscale = 1.25f / (float)ND;
  vq_main<<<N / BM, 256, 0, stream>>>(X, CB, ws_norms, ws_cb, out, loss_out, K, lscale);
}